// Round 1
// baseline (397.514 us; speedup 1.0000x reference)
//
#include <hip/hip_runtime.h>
#include <math.h>

#define B_  4
#define T_  288
#define N_  207
#define D_  152
#define FF_ 256
#define ND_ (N_*D_)      // 31464, divisible by 4
#define ND4 (ND_/4)      // 7866
#define K_  6

// ---------------- kernel 1a: column sums of Wq / Wk ----------------
__global__ void colsum_kernel(const float* __restrict__ Wq,
                              const float* __restrict__ Wk,
                              float* __restrict__ wq_sum,
                              float* __restrict__ wk_sum) {
    int j = blockIdx.x * blockDim.x + threadIdx.x;
    if (j >= ND_) return;
    const float* W  = (blockIdx.y == 0) ? Wq : Wk;
    float*       out = (blockIdx.y == 0) ? wq_sum : wk_sum;
    float s = 0.f;
    #pragma unroll 8
    for (int ff = 0; ff < FF_; ++ff) s += W[(size_t)ff * ND_ + j];
    out[j] = s;
}

// ---------------- kernel 1b: bias sums ----------------
__global__ void biassum_kernel(const float* __restrict__ bq,
                               const float* __restrict__ bk,
                               float* __restrict__ bsum) {
    __shared__ float shq[256], shk[256];
    int tid = threadIdx.x;
    shq[tid] = bq[tid];
    shk[tid] = bk[tid];
    __syncthreads();
    for (int s = 128; s > 0; s >>= 1) {
        if (tid < s) { shq[tid] += shq[tid + s]; shk[tid] += shk[tid + s]; }
        __syncthreads();
    }
    if (tid == 0) { bsum[0] = shq[0]; bsum[1] = shk[0]; }
}

// ---------------- kernel 2: sq[b,t], sk[b,t] dual dot ----------------
__global__ void rowdot_kernel(const float* __restrict__ X,
                              const float* __restrict__ wq_sum,
                              const float* __restrict__ wk_sum,
                              const float* __restrict__ bsum,
                              float* __restrict__ sq,
                              float* __restrict__ sk) {
    int row = blockIdx.x;                  // b*T_ + t, 0..1151
    int tid = threadIdx.x;
    const float4* x4 = (const float4*)(X + (size_t)row * ND_);
    const float4* q4 = (const float4*)wq_sum;
    const float4* k4 = (const float4*)wk_sum;
    float pq = 0.f, pk = 0.f;
    for (int j = tid; j < ND4; j += 256) {
        float4 xv = x4[j];
        float4 qv = q4[j];
        float4 kv = k4[j];
        pq += xv.x*qv.x + xv.y*qv.y + xv.z*qv.z + xv.w*qv.w;
        pk += xv.x*kv.x + xv.y*kv.y + xv.z*kv.z + xv.w*kv.w;
    }
    __shared__ float shq[256], shk[256];
    shq[tid] = pq; shk[tid] = pk;
    __syncthreads();
    for (int s = 128; s > 0; s >>= 1) {
        if (tid < s) { shq[tid] += shq[tid + s]; shk[tid] += shk[tid + s]; }
        __syncthreads();
    }
    if (tid == 0) {
        sq[row] = shq[0] + bsum[0];
        sk[row] = shk[0] + bsum[1];
    }
}

// ---------------- kernel 3: per-row top-K + sort-by-index ----------------
__global__ void topk_kernel(const float* __restrict__ sq,
                            const float* __restrict__ sk,
                            float* __restrict__ out_vals,   // [T_][K_]
                            float* __restrict__ out_idx_f,  // [T_][K_] (float repr)
                            int*   __restrict__ out_idx_i) {
    int t1  = blockIdx.x;
    int tid = threadIdx.x;
    __shared__ float vals[T_];
    float sq0 = sq[0*T_ + t1], sq1 = sq[1*T_ + t1];
    float sq2 = sq[2*T_ + t1], sq3 = sq[3*T_ + t1];
    for (int t2 = tid; t2 < T_; t2 += 256) {
        float c = sq0*sk[0*T_ + t2] + sq1*sk[1*T_ + t2]
                + sq2*sk[2*T_ + t2] + sq3*sk[3*T_ + t2];
        c *= (1.0f / (129.0f * (float)B_));
        vals[t2] = (t2 == t1) ? -INFINITY : c;
    }
    __syncthreads();
    if (tid == 0) {
        float tv[K_]; int ti[K_];
        for (int k = 0; k < K_; ++k) {
            float best = -INFINITY; int bi = 0;
            for (int t2 = 0; t2 < T_; ++t2) {
                if (vals[t2] > best) { best = vals[t2]; bi = t2; }  // ties -> lowest idx
            }
            tv[k] = best; ti[k] = bi;
            vals[bi] = -INFINITY;
        }
        // insertion sort by index ascending (matches argsort of indices)
        for (int a = 1; a < K_; ++a) {
            float v = tv[a]; int i = ti[a]; int b = a - 1;
            while (b >= 0 && ti[b] > i) { tv[b+1] = tv[b]; ti[b+1] = ti[b]; --b; }
            tv[b+1] = v; ti[b+1] = i;
        }
        for (int k = 0; k < K_; ++k) {
            out_vals [t1*K_ + k] = tv[k];
            out_idx_f[t1*K_ + k] = (float)ti[k];
            out_idx_i[t1*K_ + k] = ti[k];
        }
    }
}

// ---------------- kernel 4: gather X rows ----------------
// out3[b][r][k][:] = X[b][idx[r][k]][:]   (ND_ floats per row)
__global__ void gather_kernel(const float* __restrict__ X,
                              const int* __restrict__ idx,
                              float* __restrict__ out3) {
    int bid = blockIdx.x;                  // b*(T_*K_) + r*K_ + k
    int b   = bid / (T_ * K_);
    int rk  = bid % (T_ * K_);
    int src_t = idx[rk];
    const float4* src = (const float4*)(X + ((size_t)b * T_ + src_t) * ND_);
    float4*       dst = (float4*)(out3 + (size_t)bid * ND_);
    for (int j = threadIdx.x; j < ND4; j += 256) dst[j] = src[j];
}

extern "C" void kernel_launch(void* const* d_in, const int* in_sizes, int n_in,
                              void* d_out, int out_size, void* d_ws, size_t ws_size,
                              hipStream_t stream) {
    const float* X  = (const float*)d_in[0];
    const float* Wq = (const float*)d_in[1];
    const float* bq = (const float*)d_in[2];
    const float* Wk = (const float*)d_in[3];
    const float* bk = (const float*)d_in[4];
    // d_in[5] = K (constant 6, compiled in)

    float* ws = (float*)d_ws;
    float* wq_sum = ws;                       // ND_ floats (16B aligned)
    float* wk_sum = ws + ND_;                 // ND_ floats
    float* bsum   = ws + 2*ND_;               // 2 floats
    float* sq     = ws + 2*ND_ + 4;           // B_*T_ = 1152
    float* sk     = sq + B_*T_;               // 1152
    int*   idx_i  = (int*)(sk + B_*T_);       // T_*K_ = 1728 ints

    float* out_vals  = (float*)d_out;                 // 1728
    float* out_idx_f = out_vals + T_*K_;              // 1728
    float* out3      = out_idx_f + T_*K_;             // 4*288*6*31464

    dim3 g1((ND_ + 255)/256, 2);
    colsum_kernel<<<g1, 256, 0, stream>>>(Wq, Wk, wq_sum, wk_sum);
    biassum_kernel<<<1, 256, 0, stream>>>(bq, bk, bsum);
    rowdot_kernel<<<B_*T_, 256, 0, stream>>>(X, wq_sum, wk_sum, bsum, sq, sk);
    topk_kernel<<<T_, 256, 0, stream>>>(sq, sk, out_vals, out_idx_f, idx_i);
    gather_kernel<<<B_*T_*K_, 256, 0, stream>>>(X, idx_i, out3);
}

// Round 3
// 288.979 us; speedup vs baseline: 1.3756x; 1.3756x over previous
//
#include <hip/hip_runtime.h>
#include <math.h>

#define B_  4
#define T_  288
#define N_  207
#define D_  152
#define FF_ 256
#define ND_ (N_*D_)      // 31464, divisible by 4
#define ND4 (ND_/4)      // 7866
#define K_  6

// native clang vector type — accepted by __builtin_nontemporal_load/store
typedef float vfloat4 __attribute__((ext_vector_type(4)));

// ---------------- kernel 1a: column sums of Wq / Wk ----------------
// Nontemporal loads: W (64 MB) is touched exactly once; keep it out of L3
// so X stays resident for the gather. Vectorized: each thread owns one
// float4 column group, strides down 256 rows.
__global__ void colsum_kernel(const float* __restrict__ Wq,
                              const float* __restrict__ Wk,
                              float* __restrict__ wq_sum,
                              float* __restrict__ wk_sum) {
    int j = blockIdx.x * blockDim.x + threadIdx.x;   // float4 index
    if (j >= ND4) return;
    const vfloat4* W  = (const vfloat4*)((blockIdx.y == 0) ? Wq : Wk);
    vfloat4*      out = (vfloat4*)((blockIdx.y == 0) ? wq_sum : wk_sum);
    vfloat4 s = {0.f, 0.f, 0.f, 0.f};
    #pragma unroll 4
    for (int ff = 0; ff < FF_; ++ff)
        s += __builtin_nontemporal_load(&W[(size_t)ff * ND4 + j]);
    out[j] = s;
}

// ---------------- kernel 1b: bias sums ----------------
__global__ void biassum_kernel(const float* __restrict__ bq,
                               const float* __restrict__ bk,
                               float* __restrict__ bsum) {
    __shared__ float shq[256], shk[256];
    int tid = threadIdx.x;
    shq[tid] = bq[tid];
    shk[tid] = bk[tid];
    __syncthreads();
    for (int s = 128; s > 0; s >>= 1) {
        if (tid < s) { shq[tid] += shq[tid + s]; shk[tid] += shk[tid + s]; }
        __syncthreads();
    }
    if (tid == 0) { bsum[0] = shq[0]; bsum[1] = shk[0]; }
}

// ---------------- kernel 2: sq[b,t], sk[b,t] dual dot ----------------
// Normal (caching) loads of X on purpose: warms L3 for the gather.
__global__ void rowdot_kernel(const float* __restrict__ X,
                              const float* __restrict__ wq_sum,
                              const float* __restrict__ wk_sum,
                              const float* __restrict__ bsum,
                              float* __restrict__ sq,
                              float* __restrict__ sk) {
    int row = blockIdx.x;                  // b*T_ + t, 0..1151
    int tid = threadIdx.x;
    const vfloat4* x4 = (const vfloat4*)(X + (size_t)row * ND_);
    const vfloat4* q4 = (const vfloat4*)wq_sum;
    const vfloat4* k4 = (const vfloat4*)wk_sum;
    float pq = 0.f, pk = 0.f;
    for (int j = tid; j < ND4; j += 256) {
        vfloat4 xv = x4[j];
        vfloat4 qv = q4[j];
        vfloat4 kv = k4[j];
        pq += xv.x*qv.x + xv.y*qv.y + xv.z*qv.z + xv.w*qv.w;
        pk += xv.x*kv.x + xv.y*kv.y + xv.z*kv.z + xv.w*kv.w;
    }
    __shared__ float shq[256], shk[256];
    shq[tid] = pq; shk[tid] = pk;
    __syncthreads();
    for (int s = 128; s > 0; s >>= 1) {
        if (tid < s) { shq[tid] += shq[tid + s]; shk[tid] += shk[tid + s]; }
        __syncthreads();
    }
    if (tid == 0) {
        sq[row] = shq[0] + bsum[0];
        sk[row] = shk[0] + bsum[1];
    }
}

// ---------------- kernel 3: per-row top-K, wave-parallel argmax ----------------
// One 64-lane wave per row t1. Values live in 5 registers per lane
// (5*64 = 320 >= 288). 6 rounds of butterfly shfl_xor argmax,
// tie-break -> lowest index (matches lax.top_k).
#define SLOTS 5
__global__ __launch_bounds__(64) void topk_kernel(
                            const float* __restrict__ sq,
                            const float* __restrict__ sk,
                            float* __restrict__ out_vals,   // [T_][K_]
                            float* __restrict__ out_idx_f,  // [T_][K_]
                            int*   __restrict__ out_idx_i) {
    int t1   = blockIdx.x;
    int lane = threadIdx.x;
    float sq0 = sq[0*T_ + t1], sq1 = sq[1*T_ + t1];
    float sq2 = sq[2*T_ + t1], sq3 = sq[3*T_ + t1];

    float v[SLOTS]; int vi[SLOTS];
    #pragma unroll
    for (int s = 0; s < SLOTS; ++s) {
        int t2 = lane + s * 64;
        if (t2 < T_ && t2 != t1) {
            float c = sq0*sk[0*T_ + t2] + sq1*sk[1*T_ + t2]
                    + sq2*sk[2*T_ + t2] + sq3*sk[3*T_ + t2];
            v[s]  = c * (1.0f / (129.0f * (float)B_));
            vi[s] = t2;
        } else {
            v[s]  = -INFINITY;
            vi[s] = 0x7fffffff;
        }
    }

    float tv[K_]; int ti[K_];
    for (int k = 0; k < K_; ++k) {
        // local argmax over slots (tie -> lowest index)
        float bv = v[0]; int bi = vi[0];
        #pragma unroll
        for (int s = 1; s < SLOTS; ++s) {
            if (v[s] > bv || (v[s] == bv && vi[s] < bi)) { bv = v[s]; bi = vi[s]; }
        }
        // wave butterfly argmax
        #pragma unroll
        for (int off = 32; off > 0; off >>= 1) {
            float ov = __shfl_xor(bv, off);
            int   oi = __shfl_xor(bi, off);
            if (ov > bv || (ov == bv && oi < bi)) { bv = ov; bi = oi; }
        }
        tv[k] = bv; ti[k] = bi;
        // knock out the winner
        #pragma unroll
        for (int s = 0; s < SLOTS; ++s)
            if (vi[s] == bi) { v[s] = -INFINITY; vi[s] = 0x7fffffff; }
    }

    if (lane == 0) {
        // insertion sort by index ascending (matches argsort of indices)
        for (int a = 1; a < K_; ++a) {
            float vv = tv[a]; int ii = ti[a]; int b = a - 1;
            while (b >= 0 && ti[b] > ii) { tv[b+1] = tv[b]; ti[b+1] = ti[b]; --b; }
            tv[b+1] = vv; ti[b+1] = ii;
        }
        for (int k = 0; k < K_; ++k) {
            out_vals [t1*K_ + k] = tv[k];
            out_idx_f[t1*K_ + k] = (float)ti[k];
            out_idx_i[t1*K_ + k] = ti[k];
        }
    }
}

// ---------------- kernel 4: gather X rows ----------------
// out3[b][r][k][:] = X[b][idx[r][k]][:]
// Nontemporal stores: the 870 MB output stream must not allocate in L2/L3,
// or it evicts X and turns the (6x-reuse) reads into HBM reads.
__global__ void gather_kernel(const float* __restrict__ X,
                              const int* __restrict__ idx,
                              float* __restrict__ out3) {
    int bid = blockIdx.x;                  // b*(T_*K_) + r*K_ + k
    int b   = bid / (T_ * K_);
    int rk  = bid % (T_ * K_);
    int src_t = idx[rk];
    const vfloat4* src = (const vfloat4*)(X + ((size_t)b * T_ + src_t) * ND_);
    vfloat4*       dst = (vfloat4*)(out3 + (size_t)bid * ND_);
    for (int j = threadIdx.x; j < ND4; j += 256) {
        vfloat4 val = src[j];
        __builtin_nontemporal_store(val, &dst[j]);
    }
}

extern "C" void kernel_launch(void* const* d_in, const int* in_sizes, int n_in,
                              void* d_out, int out_size, void* d_ws, size_t ws_size,
                              hipStream_t stream) {
    const float* X  = (const float*)d_in[0];
    const float* Wq = (const float*)d_in[1];
    const float* bq = (const float*)d_in[2];
    const float* Wk = (const float*)d_in[3];
    const float* bk = (const float*)d_in[4];
    // d_in[5] = K (constant 6, compiled in)

    float* ws = (float*)d_ws;
    float* wq_sum = ws;                       // ND_ floats (16B aligned)
    float* wk_sum = ws + ND_;                 // ND_ floats
    float* bsum   = ws + 2*ND_;               // 2 floats
    float* sq     = ws + 2*ND_ + 4;           // B_*T_ = 1152
    float* sk     = sq + B_*T_;               // 1152
    int*   idx_i  = (int*)(sk + B_*T_);       // T_*K_ = 1728 ints

    float* out_vals  = (float*)d_out;                 // 1728
    float* out_idx_f = out_vals + T_*K_;              // 1728
    float* out3      = out_idx_f + T_*K_;             // 4*288*6*31464

    dim3 g1((ND4 + 255)/256, 2);
    colsum_kernel<<<g1, 256, 0, stream>>>(Wq, Wk, wq_sum, wk_sum);
    biassum_kernel<<<1, 256, 0, stream>>>(bq, bk, bsum);
    rowdot_kernel<<<B_*T_, 256, 0, stream>>>(X, wq_sum, wk_sum, bsum, sq, sk);
    topk_kernel<<<T_, 64, 0, stream>>>(sq, sk, out_vals, out_idx_f, idx_i);
    gather_kernel<<<B_*T_*K_, 256, 0, stream>>>(X, idx_i, out3);
}